// Round 4
// baseline (121.781 us; speedup 1.0000x reference)
//
#include <hip/hip_runtime.h>
#include <cstddef>

// Problem constants
#define SS 64
#define NN 128
#define LL 10
#define DD 300
#define HH 150
#define HP 160           // H padded to 160 (16B-aligned float4 rows)
#define CC 16            // positions per output block
#define RMAX (CC + LL - 1)

// Workspace layout (in floats)
#define WS_SC  0                         // S*N = 8192 floats
#define WS_W1P (WS_SC + SS*NN)           // D*HP = 48000 floats
#define WS_BW  (WS_W1P + DD*HP)          // 2*HP = 320 floats (b1 pad | W2 pad)

typedef float vf4 __attribute__((ext_vector_type(4)));  // native vec for nt-store

__device__ __forceinline__ void fma4(float4& a, float s, const float4 b) {
    a.x = fmaf(s, b.x, a.x);
    a.y = fmaf(s, b.y, a.y);
    a.z = fmaf(s, b.z, a.z);
    a.w = fmaf(s, b.w, a.w);
}

__device__ __forceinline__ void nt_store4(float* p, const float4 v) {
    vf4 t = {v.x, v.y, v.z, v.w};
    __builtin_nontemporal_store(t, (vf4*)p);
}

// ---------------- Kernel 0: pad weights into workspace ----------------
__global__ void pad_weights(const float* __restrict__ W1, const float* __restrict__ b1,
                            const float* __restrict__ W2, float* __restrict__ W1p,
                            float* __restrict__ bW) {
    int idx = blockIdx.x * 256 + threadIdx.x;
    if (idx < DD * HP) {
        int d = idx / HP, j = idx - d * HP;
        W1p[idx] = (j < HH) ? W1[d * HH + j] : 0.f;
    }
    if (idx < HP) {
        bW[idx] = (idx < HH) ? b1[idx] : 0.f;
    } else if (idx < 2 * HP) {
        int j = idx - HP;
        bW[idx] = (j < HH) ? W2[j] : 0.f;
    }
}

// ---------------- Kernel 1: gather embeddings + MLP scores ----------------
constexpr int TB = 32;

__global__ __launch_bounds__(256) void k_scores(
        const int* __restrict__ tokens, const float* __restrict__ table,
        const float* __restrict__ W1p, const float* __restrict__ bW,
        const float* __restrict__ b2, float* __restrict__ ws_sc)
{
    __shared__ float lemb[TB][DD + 4];   // row stride 304 floats
    __shared__ float lpart[TB][40];      // 38 j-groups used
    __shared__ int   ltok[TB];

    const int tid = threadIdx.x;
    const int t0  = blockIdx.x * TB;

    if (tid < TB) ltok[tid] = tokens[t0 + tid];
    __syncthreads();

    for (int l = tid; l < TB * 75; l += 256) {
        const int t = l / 75, q = l - t * 75;
        *(float4*)&lemb[t][q * 4] = *(const float4*)(table + (size_t)ltok[t] * DD + q * 4);
    }
    __syncthreads();

    // 8 token-groups x 38 j-groups; each slot: 4 tokens x 4 j's.
    for (int slot = tid; slot < 8 * 38; slot += 256) {
        const int tg = slot / 38;
        const int jg = slot - tg * 38;
        const int j0 = jg * 4;
        const int tt = tg * 4;

        float4 acc0 = {0,0,0,0}, acc1 = {0,0,0,0}, acc2 = {0,0,0,0}, acc3 = {0,0,0,0};
        const float* wp = W1p + j0;

        #pragma unroll 5
        for (int d = 0; d < DD; d += 4) {
            const float4 e0 = *(const float4*)&lemb[tt + 0][d];
            const float4 e1 = *(const float4*)&lemb[tt + 1][d];
            const float4 e2 = *(const float4*)&lemb[tt + 2][d];
            const float4 e3 = *(const float4*)&lemb[tt + 3][d];
            const float4 w0 = *(const float4*)(wp + (size_t)(d + 0) * HP);
            const float4 w1 = *(const float4*)(wp + (size_t)(d + 1) * HP);
            const float4 w2 = *(const float4*)(wp + (size_t)(d + 2) * HP);
            const float4 w3 = *(const float4*)(wp + (size_t)(d + 3) * HP);
            fma4(acc0, e0.x, w0); fma4(acc0, e0.y, w1); fma4(acc0, e0.z, w2); fma4(acc0, e0.w, w3);
            fma4(acc1, e1.x, w0); fma4(acc1, e1.y, w1); fma4(acc1, e1.z, w2); fma4(acc1, e1.w, w3);
            fma4(acc2, e2.x, w0); fma4(acc2, e2.y, w1); fma4(acc2, e2.z, w2); fma4(acc2, e2.w, w3);
            fma4(acc3, e3.x, w0); fma4(acc3, e3.y, w1); fma4(acc3, e3.z, w2); fma4(acc3, e3.w, w3);
        }

        const float4 bb = *(const float4*)(bW + j0);
        const float4 v2 = *(const float4*)(bW + HP + j0);

        #define RELD(A) (fmaxf((A).x + bb.x, 0.f) * v2.x + \
                         fmaxf((A).y + bb.y, 0.f) * v2.y + \
                         fmaxf((A).z + bb.z, 0.f) * v2.z + \
                         fmaxf((A).w + bb.w, 0.f) * v2.w)
        lpart[tt + 0][jg] = RELD(acc0);
        lpart[tt + 1][jg] = RELD(acc1);
        lpart[tt + 2][jg] = RELD(acc2);
        lpart[tt + 3][jg] = RELD(acc3);
        #undef RELD
    }
    __syncthreads();

    if (tid < TB) {
        float s = 0.f;
        #pragma unroll
        for (int jg = 0; jg < 38; ++jg) s += lpart[tid][jg];
        ws_sc[t0 + tid] = s + b2[0];
    }
}

// ---------------- Kernel 2: gather + softmax + output (16 positions/block) ----
__global__ __launch_bounds__(256) void k_out(
        const int* __restrict__ tokens, const float* __restrict__ table,
        const float* __restrict__ ws_sc, float* __restrict__ out)
{
    const int bid = blockIdx.x;          // s*8 + chunk
    const int s   = bid >> 3;
    const int i0  = (bid & 7) * CC;
    const int R   = min(RMAX, NN - i0);  // emb rows staged

    __shared__ float le[RMAX][DD + 4];   // window embeddings, stride 304
    __shared__ float lp[CC][LL][12];     // probs
    __shared__ float sc_l[RMAX];

    const int tid = threadIdx.x;

    if (tid < R) sc_l[tid] = ws_sc[s * NN + i0 + tid];

    const int* tk = tokens + s * NN + i0;
    for (int l = tid; l < R * 75; l += 256) {
        const int k = l / 75, q = l - k * 75;
        *(float4*)&le[k][q * 4] = *(const float4*)(table + (size_t)tk[k] * DD + q * 4);
    }
    __syncthreads();

    // 160 softmax rows, one thread each; 3-pass from LDS (no local arrays).
    if (tid < CC * LL) {
        const int li = tid / LL, w = tid - li * LL;
        const int nk = min(LL, NN - (i0 + li));
        if (w < nk) {
            float m = -1e30f;
            for (int k = 0; k <= w; ++k) m = fmaxf(m, sc_l[li + k]);
            float sum = 0.f;
            for (int k = 0; k <= w; ++k) sum += __expf(sc_l[li + k] - m);
            const float inv = 1.f / sum;
            for (int k = 0; k <= w; ++k) lp[li][w][k] = __expf(sc_l[li + k] - m) * inv;
        }
    }
    __syncthreads();

    // Stream 16*9000 floats = 9000 float4 NT stores per block, coalesced.
    // Output is write-only (295 MB > L3): non-temporal avoids write-allocate
    // thrash through L2/L3.
    float* dst = out + (size_t)(s * NN + i0) * (LL * 3 * DD);
    for (int o4 = tid; o4 < CC * 2250; o4 += 256) {
        const int li = o4 / 2250;
        const int r  = o4 - li * 2250;
        const int w  = r / 225;
        const int c4 = r - w * 225;
        const int c  = c4 * 4;
        const int nk = min(LL, NN - (i0 + li));
        float4 v;
        if (w >= nk) {
            v = make_float4(0.f, 0.f, 0.f, 0.f);
        } else if (c < DD) {
            v = *(const float4*)&le[li][c];              // first = emb[i]
        } else if (c < 2 * DD) {
            v = *(const float4*)&le[li + w][c - DD];     // last = emb[i+w]
        } else {
            const int cc = c - 2 * DD;                   // head
            float4 a = make_float4(0.f, 0.f, 0.f, 0.f);
            for (int k = 0; k <= w; ++k) {
                fma4(a, lp[li][w][k], *(const float4*)&le[li + k][cc]);
            }
            v = a;
        }
        nt_store4(dst + (size_t)o4 * 4, v);
    }
}

// ---------------- Launch ----------------
extern "C" void kernel_launch(void* const* d_in, const int* in_sizes, int n_in,
                              void* d_out, int out_size, void* d_ws, size_t ws_size,
                              hipStream_t stream) {
    const int*   tokens = (const int*)d_in[0];
    const float* table  = (const float*)d_in[1];
    const float* W1     = (const float*)d_in[2];
    const float* b1     = (const float*)d_in[3];
    const float* W2     = (const float*)d_in[4];
    const float* b2     = (const float*)d_in[5];
    float* out = (float*)d_out;
    float* ws  = (float*)d_ws;

    float* ws_sc = ws + WS_SC;
    float* W1p   = ws + WS_W1P;
    float* bW    = ws + WS_BW;

    pad_weights<<<(DD * HP + 255) / 256, 256, 0, stream>>>(W1, b1, W2, W1p, bW);
    k_scores<<<(SS * NN) / TB, 256, 0, stream>>>(tokens, table, W1p, bW, b2, ws_sc);
    k_out<<<SS * (NN / CC), 256, 0, stream>>>(tokens, table, ws_sc, out);
}

// Round 5
// 116.487 us; speedup vs baseline: 1.0454x; 1.0454x over previous
//
#include <hip/hip_runtime.h>
#include <cstddef>

// Problem constants
#define SS 64
#define NN 128
#define LL 10
#define DD 300
#define HH 150
#define HP 152           // H padded to 152 = 19*8 (16B-aligned float4 pairs)
#define CC 16            // positions per block
#define RMAX (CC + LL - 1)   // 25 emb rows staged
#define JG 19            // j-groups of 8
#define TG 13            // token-pairs (ceil(25/2))

// Workspace layout (floats)
#define WS_W1P 0                 // D*HP = 45600
#define WS_BW  (DD*HP)           // 2*HP = 304 (b1 pad | W2 pad)

typedef float vf4 __attribute__((ext_vector_type(4)));

__device__ __forceinline__ void fma4(float4& a, float s, const float4 b) {
    a.x = fmaf(s, b.x, a.x);
    a.y = fmaf(s, b.y, a.y);
    a.z = fmaf(s, b.z, a.z);
    a.w = fmaf(s, b.w, a.w);
}

__device__ __forceinline__ void nt_store4(float* p, const float4 v) {
    vf4 t = {v.x, v.y, v.z, v.w};
    __builtin_nontemporal_store(t, (vf4*)p);
}

// ---------------- Kernel 0: pad weights ----------------
__global__ void pad_weights(const float* __restrict__ W1, const float* __restrict__ b1,
                            const float* __restrict__ W2, float* __restrict__ W1p,
                            float* __restrict__ bW) {
    int idx = blockIdx.x * 256 + threadIdx.x;
    if (idx < DD * HP) {
        int d = idx / HP, j = idx - d * HP;
        W1p[idx] = (j < HH) ? W1[d * HH + j] : 0.f;
    }
    if (idx < HP) {
        bW[idx] = (idx < HH) ? b1[idx] : 0.f;
    } else if (idx < 2 * HP) {
        int j = idx - HP;
        bW[idx] = (j < HH) ? W2[j] : 0.f;
    }
}

// ---------------- Fused kernel: gather + MLP + softmax + store ----------------
__global__ __launch_bounds__(256) void k_fused(
        const int* __restrict__ tokens, const float* __restrict__ table,
        const float* __restrict__ W1p, const float* __restrict__ bW,
        const float* __restrict__ b2, float* __restrict__ out)
{
    const int bid = blockIdx.x;          // s*8 + chunk
    const int s   = bid >> 3;
    const int i0  = (bid & 7) * CC;
    const int R   = min(RMAX, NN - i0);  // emb rows staged (25 or 16)

    __shared__ float le[RMAX][DD + 4];   // stride 304 floats
    __shared__ float lp[CC][LL][12];     // probs
    __shared__ float lpart[RMAX][20];    // 19 j-group partials per token
    __shared__ float sc_l[RMAX];
    __shared__ int   ltok[RMAX];

    const int tid = threadIdx.x;

    if (tid < R) ltok[tid] = tokens[s * NN + i0 + tid];
    __syncthreads();

    // ---- gather R emb rows (75 float4 each) ----
    for (int l = tid; l < R * 75; l += 256) {
        const int t = l / 75, q = l - t * 75;
        *(float4*)&le[t][q * 4] = *(const float4*)(table + (size_t)ltok[t] * DD + q * 4);
    }
    __syncthreads();

    // ---- MLP scores: 247 slots = 13 token-pairs x 19 j-octets, 1 slot/thread ----
    if (tid < TG * JG) {
        const int tg = tid / JG;
        const int jg = tid - tg * JG;
        const int t0 = tg * 2;
        if (t0 < R) {
            const int t1 = (t0 + 1 < R) ? (t0 + 1) : t0;   // clamp, discard write
            const int j0 = jg * 8;
            const float* wp = W1p + j0;

            float4 a0l = {0,0,0,0}, a0h = {0,0,0,0}, a1l = {0,0,0,0}, a1h = {0,0,0,0};
            #pragma unroll 5
            for (int d = 0; d < DD; d += 4) {
                const float4 e0 = *(const float4*)&le[t0][d];
                const float4 e1 = *(const float4*)&le[t1][d];
                const float4 wa0 = *(const float4*)(wp + (size_t)(d + 0) * HP);
                const float4 wb0 = *(const float4*)(wp + (size_t)(d + 0) * HP + 4);
                const float4 wa1 = *(const float4*)(wp + (size_t)(d + 1) * HP);
                const float4 wb1 = *(const float4*)(wp + (size_t)(d + 1) * HP + 4);
                const float4 wa2 = *(const float4*)(wp + (size_t)(d + 2) * HP);
                const float4 wb2 = *(const float4*)(wp + (size_t)(d + 2) * HP + 4);
                const float4 wa3 = *(const float4*)(wp + (size_t)(d + 3) * HP);
                const float4 wb3 = *(const float4*)(wp + (size_t)(d + 3) * HP + 4);
                fma4(a0l, e0.x, wa0); fma4(a0h, e0.x, wb0);
                fma4(a0l, e0.y, wa1); fma4(a0h, e0.y, wb1);
                fma4(a0l, e0.z, wa2); fma4(a0h, e0.z, wb2);
                fma4(a0l, e0.w, wa3); fma4(a0h, e0.w, wb3);
                fma4(a1l, e1.x, wa0); fma4(a1h, e1.x, wb0);
                fma4(a1l, e1.y, wa1); fma4(a1h, e1.y, wb1);
                fma4(a1l, e1.z, wa2); fma4(a1h, e1.z, wb2);
                fma4(a1l, e1.w, wa3); fma4(a1h, e1.w, wb3);
            }
            const float4 bl = *(const float4*)(bW + j0);
            const float4 bh = *(const float4*)(bW + j0 + 4);
            const float4 vl = *(const float4*)(bW + HP + j0);
            const float4 vh = *(const float4*)(bW + HP + j0 + 4);

            #define RELD(A, B, V) (fmaxf((A).x + (B).x, 0.f) * (V).x + \
                                   fmaxf((A).y + (B).y, 0.f) * (V).y + \
                                   fmaxf((A).z + (B).z, 0.f) * (V).z + \
                                   fmaxf((A).w + (B).w, 0.f) * (V).w)
            lpart[t0][jg] = RELD(a0l, bl, vl) + RELD(a0h, bh, vh);
            if (t0 + 1 < R) lpart[t0 + 1][jg] = RELD(a1l, bl, vl) + RELD(a1h, bh, vh);
            #undef RELD
        }
    }
    __syncthreads();

    // ---- reduce 19 partials per token ----
    if (tid < R) {
        float sum = 0.f;
        #pragma unroll
        for (int jg = 0; jg < JG; ++jg) sum += lpart[tid][jg];
        sc_l[tid] = sum + b2[0];
    }
    __syncthreads();

    // ---- 160 softmax rows, 3-pass from LDS ----
    if (tid < CC * LL) {
        const int li = tid / LL, w = tid - li * LL;
        const int nk = min(LL, NN - (i0 + li));
        if (w < nk) {
            float m = -1e30f;
            for (int k = 0; k <= w; ++k) m = fmaxf(m, sc_l[li + k]);
            float sum = 0.f;
            for (int k = 0; k <= w; ++k) sum += __expf(sc_l[li + k] - m);
            const float inv = 1.f / sum;
            for (int k = 0; k <= w; ++k) lp[li][w][k] = __expf(sc_l[li + k] - m) * inv;
        }
    }
    __syncthreads();

    // ---- stream 36000 float4 NT stores, coalesced ----
    float* dst = out + (size_t)(s * NN + i0) * (LL * 3 * DD);
    for (int o4 = tid; o4 < CC * 2250; o4 += 256) {
        const int li = o4 / 2250;
        const int r  = o4 - li * 2250;
        const int w  = r / 225;
        const int c4 = r - w * 225;
        const int c  = c4 * 4;
        const int nk = min(LL, NN - (i0 + li));
        float4 v;
        if (w >= nk) {
            v = make_float4(0.f, 0.f, 0.f, 0.f);
        } else if (c < DD) {
            v = *(const float4*)&le[li][c];              // first = emb[i]
        } else if (c < 2 * DD) {
            v = *(const float4*)&le[li + w][c - DD];     // last = emb[i+w]
        } else {
            const int cc = c - 2 * DD;                   // head
            float4 a = make_float4(0.f, 0.f, 0.f, 0.f);
            for (int k = 0; k <= w; ++k) {
                fma4(a, lp[li][w][k], *(const float4*)&le[li + k][cc]);
            }
            v = a;
        }
        nt_store4(dst + (size_t)o4 * 4, v);
    }
}

// ---------------- Launch ----------------
extern "C" void kernel_launch(void* const* d_in, const int* in_sizes, int n_in,
                              void* d_out, int out_size, void* d_ws, size_t ws_size,
                              hipStream_t stream) {
    const int*   tokens = (const int*)d_in[0];
    const float* table  = (const float*)d_in[1];
    const float* W1     = (const float*)d_in[2];
    const float* b1     = (const float*)d_in[3];
    const float* W2     = (const float*)d_in[4];
    const float* b2     = (const float*)d_in[5];
    float* out = (float*)d_out;
    float* ws  = (float*)d_ws;

    float* W1p = ws + WS_W1P;
    float* bW  = ws + WS_BW;

    pad_weights<<<(DD * HP + 255) / 256, 256, 0, stream>>>(W1, b1, W2, W1p, bW);
    k_fused<<<SS * (NN / CC), 256, 0, stream>>>(tokens, table, W1p, bW, b2, out);
}